// Round 9
// baseline (282.724 us; speedup 1.0000x reference)
//
#include <hip/hip_runtime.h>
#include <math.h>

// ---------------------------------------------------------------------------
// Bidirectional Mamba block, MI355X. Round 9:
//  - scan v2: no LDS, no barriers. Direct global f32x4 loads (D/U broadcast,
//    B/C rows L2-resident), 8-step register groups, DPP mirror reduce,
//    y stored by n==0 lanes as masked f32x4 (sequential per row).
//  - dt_proj -> fp16 MFMA (single BK=64 step): A = xdbl^T staged in-kernel
//    (verified x_proj pattern), B = dw16 via global_load_lds, softplus+bias
//    epilogue fused into C-store. f32 gemm removed.
//  - in/out_proj MFMA, conv, x_proj, combine unchanged (verified r8).
// ws layout (f32 elements):
//   xz    [b][4096][1024]           8,388,608
//   u     [dirb][2048][1024]        8,388,608  (head: H16/Win16 before conv)
//   xdbl  [dirb][96][1024]            393,216
//   delta [dirb][2048][1024]        8,388,608  (head: x_proj partials before
//                                               dt_proj; GT fp16 after scan)
//   y     [dirb][2048][1024]        8,388,608  (head: dw16/bcat/xw16 scratch,
//                                               Wout16 after combine)
// ---------------------------------------------------------------------------

typedef _Float16 f16x8 __attribute__((ext_vector_type(8)));
typedef _Float16 f16x4 __attribute__((ext_vector_type(4)));
typedef float    f32x4 __attribute__((ext_vector_type(4)));

__device__ __forceinline__ void gload_lds16(const void* g, void* l) {
    __builtin_amdgcn_global_load_lds(
        (const __attribute__((address_space(1))) void*)g,
        (__attribute__((address_space(3))) void*)l, 16, 0, 0);
}

__device__ __forceinline__ float softplus_f(float x) {
    float e = __builtin_amdgcn_exp2f(-fabsf(x) * 1.44269504f);
    return fmaxf(x, 0.f) + __builtin_amdgcn_logf(1.f + e) * 0.69314718f;
}

template<int CTRL>
__device__ __forceinline__ float dpp_add(float x) {
    int s = __builtin_amdgcn_update_dpp(0, __builtin_bit_cast(int, x),
                                        CTRL, 0xF, 0xF, true);
    return x + __builtin_bit_cast(float, s);
}

// ---------------------------------------------------------------------------
// fp16 NT MFMA GEMM (in_proj / out_proj): A MxK, B NxK (both K-contig),
// C[n*ldc+m] f32. global_load_lds staging, pre-swizzled source (rule #21).
// ---------------------------------------------------------------------------
template<int WMW, int WNW, int FM, int FN>
__global__ __launch_bounds__(256)
void gemm_nt_f16(const _Float16* __restrict__ A, const _Float16* __restrict__ B,
                 float* __restrict__ C, int K, int ldc, long sA, long sC)
{
    constexpr int BM = WMW * FM * 16, BN = WNW * FN * 16;
    constexpr int ACH = BM / 8, NCH = (BM + BN) / 8;
    __shared__ __align__(16) _Float16 lds[(BM + BN) * 64];
    A += (long)blockIdx.z * sA;
    C += (long)blockIdx.z * sC;
    const int m0 = blockIdx.y * BM, n0 = blockIdx.x * BN;
    const int t = threadIdx.x, wid = t >> 6, lane = t & 63;
    const int wm = wid / WNW, wn = wid % WNW;
    const int srow = lane >> 3;
    const int skk  = ((lane & 7) ^ srow) * 8;

    f32x4 acc[FM][FN];
#pragma unroll
    for (int i = 0; i < FM; ++i)
#pragma unroll
        for (int j = 0; j < FN; ++j) acc[i][j] = (f32x4){0.f, 0.f, 0.f, 0.f};

    for (int k0 = 0; k0 < K; k0 += 64) {
#pragma unroll
        for (int c = wid; c < NCH; c += 4) {
            const _Float16* gp = (c < ACH)
                ? A + (long)(m0 + c * 8 + srow) * K + k0 + skk
                : B + (long)(n0 + (c - ACH) * 8 + srow) * K + k0 + skk;
            gload_lds16(gp, lds + c * 512);
        }
        __syncthreads();
#pragma unroll
        for (int kw = 0; kw < 2; ++kw) {
            f16x8 af[FM], bf[FN];
#pragma unroll
            for (int i = 0; i < FM; ++i) {
                int r = wm * FM * 16 + i * 16 + (lane & 15);
                af[i] = *(const f16x8*)(lds + r * 64 +
                        (((kw * 4 + (lane >> 4)) ^ (r & 7)) * 8));
            }
#pragma unroll
            for (int j = 0; j < FN; ++j) {
                int r = wn * FN * 16 + j * 16 + (lane & 15);
                bf[j] = *(const f16x8*)(lds + BM * 64 + r * 64 +
                        (((kw * 4 + (lane >> 4)) ^ (r & 7)) * 8));
            }
#pragma unroll
            for (int i = 0; i < FM; ++i)
#pragma unroll
                for (int j = 0; j < FN; ++j)
                    acc[i][j] = __builtin_amdgcn_mfma_f32_16x16x32_f16(
                        af[i], bf[j], acc[i][j], 0, 0, 0);
        }
        __syncthreads();
    }
#pragma unroll
    for (int i = 0; i < FM; ++i)
#pragma unroll
        for (int j = 0; j < FN; ++j) {
            int n = n0 + wn * FN * 16 + j * 16 + (lane & 15);
            int m = m0 + wm * FM * 16 + i * 16 + (lane >> 4) * 4;
            *(f32x4*)&C[(long)n * ldc + m] = acc[i][j];
        }
}

// ---------------------------------------------------------------------------
// x_proj fp16 MFMA, split-K (verified r8). A = u^T staged in-kernel,
// B = xw16 via global_load_lds. Partials -> pb.
// ---------------------------------------------------------------------------
#define XP_SK 8
__global__ __launch_bounds__(256)
void xproj_f16_kernel(const float* __restrict__ u, const _Float16* __restrict__ xw16,
                      float* __restrict__ pb)
{
    __shared__ __align__(16) _Float16 Asw[128 * 64];
    __shared__ __align__(16) _Float16 Bsw[96 * 64];
    const int t = threadIdx.x, wid = t >> 6, lane = t & 63;
    const int wm = wid >> 1, wn = wid & 1;
    const int m0 = blockIdx.x * 128;
    const int sk = blockIdx.y, dirb = blockIdx.z;
    const float* ub = u + (long)dirb * 2048 * 1024;
    const _Float16* Bw = xw16 + (long)(dirb >> 1) * 96 * 2048;
    const int srow = lane >> 3;
    const int skk  = ((lane & 7) ^ srow) * 8;
    const int lloc = (t & 31) * 4;
    const int kslt = t >> 5;

    f32x4 acc[4][3];
#pragma unroll
    for (int i = 0; i < 4; ++i)
#pragma unroll
        for (int j = 0; j < 3; ++j) acc[i][j] = (f32x4){0.f, 0.f, 0.f, 0.f};

    for (int ks = 0; ks < 2048 / XP_SK; ks += 64) {
        const int k0 = sk * (2048 / XP_SK) + ks;
#pragma unroll
        for (int c = wid; c < 12; c += 4)
            gload_lds16(Bw + (long)(c * 8 + srow) * 2048 + k0 + skk, Bsw + c * 512);
        float av[8][4];
#pragma unroll
        for (int kk = 0; kk < 8; ++kk) {
            f32x4 v = *(const f32x4*)&ub[(long)(k0 + kslt * 8 + kk) * 1024 + m0 + lloc];
            av[kk][0] = v.x; av[kk][1] = v.y; av[kk][2] = v.z; av[kk][3] = v.w;
        }
#pragma unroll
        for (int q = 0; q < 4; ++q) {
            int l = lloc + q;
            f16x8 h = {(_Float16)av[0][q], (_Float16)av[1][q], (_Float16)av[2][q],
                       (_Float16)av[3][q], (_Float16)av[4][q], (_Float16)av[5][q],
                       (_Float16)av[6][q], (_Float16)av[7][q]};
            *(f16x8*)(Asw + l * 64 + ((kslt ^ (l & 7)) * 8)) = h;
        }
        __syncthreads();
#pragma unroll
        for (int kw = 0; kw < 2; ++kw) {
            f16x8 af[4], bf[3];
#pragma unroll
            for (int i = 0; i < 4; ++i) {
                int r = wm * 64 + i * 16 + (lane & 15);
                af[i] = *(const f16x8*)(Asw + r * 64 +
                        (((kw * 4 + (lane >> 4)) ^ (r & 7)) * 8));
            }
#pragma unroll
            for (int j = 0; j < 3; ++j) {
                int r = wn * 48 + j * 16 + (lane & 15);
                bf[j] = *(const f16x8*)(Bsw + r * 64 +
                        (((kw * 4 + (lane >> 4)) ^ (r & 7)) * 8));
            }
#pragma unroll
            for (int i = 0; i < 4; ++i)
#pragma unroll
                for (int j = 0; j < 3; ++j)
                    acc[i][j] = __builtin_amdgcn_mfma_f32_16x16x32_f16(
                        af[i], bf[j], acc[i][j], 0, 0, 0);
        }
        __syncthreads();
    }
    float* Cp = pb + ((long)sk * 4 + dirb) * 96 * 1024;
#pragma unroll
    for (int i = 0; i < 4; ++i)
#pragma unroll
        for (int j = 0; j < 3; ++j) {
            int n = wn * 48 + j * 16 + (lane & 15);
            int m = m0 + wm * 64 + i * 16 + (lane >> 4) * 4;
            *(f32x4*)&Cp[(long)n * 1024 + m] = acc[i][j];
        }
}

// Sum XP_SK split-K partials -> xdbl
__global__ __launch_bounds__(256)
void xreduce_kernel(const float* __restrict__ pb, float* __restrict__ xdbl)
{
    int f = (blockIdx.x * 256 + threadIdx.x) * 4;
    f32x4 s = (f32x4){0.f, 0.f, 0.f, 0.f};
#pragma unroll
    for (int sk = 0; sk < XP_SK; ++sk)
        s += *(const f32x4*)(pb + (long)sk * 393216 + f);
    *(f32x4*)(xdbl + f) = s;
}

// ---------------------------------------------------------------------------
// dt_proj fp16 MFMA: delta[d][l] = softplus(sum_r W[d][r]*xdbl[r][l] + bias[d]).
// One BK=64 step. A = xdbl^T (l rows) staged in-kernel; B = dw16 via
// global_load_lds (pre-swizzled source). grid (16 d-tiles, 8 l-tiles, 4 dirb).
// ---------------------------------------------------------------------------
__global__ __launch_bounds__(256)
void dtproj_f16_kernel(const float* __restrict__ xdbl, const _Float16* __restrict__ dw16,
                       const float* __restrict__ bcat, float* __restrict__ delta)
{
    __shared__ __align__(16) _Float16 Asw[128 * 64];
    __shared__ __align__(16) _Float16 Bsw[128 * 64];
    const int t = threadIdx.x, wid = t >> 6, lane = t & 63;
    const int wm = wid >> 1, wn = wid & 1;
    const int n0 = blockIdx.x * 128, m0 = blockIdx.y * 128;
    const int dirb = blockIdx.z, dir = dirb >> 1;
    const float* Xb = xdbl + (long)dirb * 96 * 1024;
    const _Float16* Bw = dw16 + (long)dir * 2048 * 64;
    const int srow = lane >> 3, skk = ((lane & 7) ^ srow) * 8;
    const int lloc = (t & 31) * 4, kslt = t >> 5;

    // B: 16 chunks of 8 d-rows x 64 r
#pragma unroll
    for (int c = wid; c < 16; c += 4)
        gload_lds16(Bw + (long)(n0 + c * 8 + srow) * 64 + skk, Bsw + c * 512);
    // A: xdbl^T — read 8 r x 4 l, cvt fp16, swizzled transpose-store
    float av[8][4];
#pragma unroll
    for (int kk = 0; kk < 8; ++kk) {
        f32x4 v = *(const f32x4*)&Xb[(long)(kslt * 8 + kk) * 1024 + m0 + lloc];
        av[kk][0] = v.x; av[kk][1] = v.y; av[kk][2] = v.z; av[kk][3] = v.w;
    }
#pragma unroll
    for (int q = 0; q < 4; ++q) {
        int l = lloc + q;
        f16x8 h = {(_Float16)av[0][q], (_Float16)av[1][q], (_Float16)av[2][q],
                   (_Float16)av[3][q], (_Float16)av[4][q], (_Float16)av[5][q],
                   (_Float16)av[6][q], (_Float16)av[7][q]};
        *(f16x8*)(Asw + l * 64 + ((kslt ^ (l & 7)) * 8)) = h;
    }
    __syncthreads();

    f32x4 acc[4][4];
#pragma unroll
    for (int i = 0; i < 4; ++i)
#pragma unroll
        for (int j = 0; j < 4; ++j) acc[i][j] = (f32x4){0.f, 0.f, 0.f, 0.f};
#pragma unroll
    for (int kw = 0; kw < 2; ++kw) {
        f16x8 af[4], bf[4];
#pragma unroll
        for (int i = 0; i < 4; ++i) {
            int r = wm * 64 + i * 16 + (lane & 15);
            af[i] = *(const f16x8*)(Asw + r * 64 +
                    (((kw * 4 + (lane >> 4)) ^ (r & 7)) * 8));
        }
#pragma unroll
        for (int j = 0; j < 4; ++j) {
            int r = wn * 64 + j * 16 + (lane & 15);
            bf[j] = *(const f16x8*)(Bsw + r * 64 +
                    (((kw * 4 + (lane >> 4)) ^ (r & 7)) * 8));
        }
#pragma unroll
        for (int i = 0; i < 4; ++i)
#pragma unroll
            for (int j = 0; j < 4; ++j)
                acc[i][j] = __builtin_amdgcn_mfma_f32_16x16x32_f16(
                    af[i], bf[j], acc[i][j], 0, 0, 0);
    }
    float* Dp = delta + (long)dirb * 2048 * 1024;
#pragma unroll
    for (int j = 0; j < 4; ++j) {
        int dd = n0 + wn * 64 + j * 16 + (lane & 15);
        float bm = bcat[dir * 2048 + dd];
#pragma unroll
        for (int i = 0; i < 4; ++i) {
            int m = m0 + wm * 64 + i * 16 + (lane >> 4) * 4;
            f32x4 v = acc[i][j];
            f32x4 o = {softplus_f(v.x + bm), softplus_f(v.y + bm),
                       softplus_f(v.z + bm), softplus_f(v.w + bm)};
            *(f32x4*)&Dp[(long)dd * 1024 + m] = o;
        }
    }
}

// f32 -> fp16 elementwise
__global__ __launch_bounds__(256)
void cvt_f16_kernel(const float* __restrict__ in, _Float16* __restrict__ out, int n)
{
    int i = (blockIdx.x * 256 + threadIdx.x) * 4;
    if (i + 3 < n) {
        float4 v = *(const float4*)(in + i);
        f16x4 h = {(_Float16)v.x, (_Float16)v.y, (_Float16)v.z, (_Float16)v.w};
        *(f16x4*)(out + i) = h;
    }
}

// Concat weights: x_proj fp16, dt_proj fp16, dt bias f32.
__global__ __launch_bounds__(256)
void concat_weights(const float* __restrict__ xwf, const float* __restrict__ xwb,
                    const float* __restrict__ dwf, const float* __restrict__ dwb,
                    const float* __restrict__ bf,  const float* __restrict__ bb,
                    _Float16* __restrict__ xw16, _Float16* __restrict__ dw16,
                    float* __restrict__ bcat)
{
    int i = blockIdx.x * 256 + threadIdx.x;
    if (i < 196608) { xw16[i] = (_Float16)xwf[i]; xw16[196608 + i] = (_Float16)xwb[i]; }
    if (i < 131072) { dw16[i] = (_Float16)dwf[i]; dw16[131072 + i] = (_Float16)dwb[i]; }
    if (i < 2048)   { bcat[i]  = bf[i];  bcat[2048 + i] = bb[i]; }
}

// Depthwise causal conv (k=4) + SiLU, both directions (bwd in reversed coords).
__global__ __launch_bounds__(256)
void conv_silu_kernel(const float* __restrict__ xz,
                      const float* __restrict__ wf, const float* __restrict__ bf,
                      const float* __restrict__ wb, const float* __restrict__ bbk,
                      float* __restrict__ u)
{
    long idx = (long)blockIdx.x * 256 + threadIdx.x;   // (dir,b,d,l)
    int l = (int)(idx & 1023);
    long r = idx >> 10;
    int d = (int)(r & 2047);
    int b = (int)((r >> 11) & 1);
    int dir = (int)(r >> 12);
    const float* x = xz + ((long)b * 4096 + d) * 1024;
    const float* w = dir ? wb : wf;
    float s = dir ? bbk[d] : bf[d];
    if (dir == 0) {
#pragma unroll
        for (int j = 0; j < 4; ++j) {
            int p = l - 3 + j;
            if (p >= 0) s = fmaf(w[d * 4 + j], x[p], s);
        }
    } else {
#pragma unroll
        for (int j = 0; j < 4; ++j) {
            int src = l - 3 + j;
            if (src >= 0) s = fmaf(w[d * 4 + j], x[1023 - src], s);
        }
    }
    u[idx] = s / (1.f + __builtin_amdgcn_exp2f(-s * 1.44269504f));
}

// ---------------------------------------------------------------------------
// Fused selective scan v2: no LDS, no barriers. 256 th = 16 d x 16 n.
// Direct global f32x4 loads (D/U broadcast across n-lanes; B/C per-lane rows,
// all L2/L3-resident). 8-step register groups. DPP mirror-butterfly reduce
// (verified). y stored by n==0 lanes as masked f32x4 (row-sequential).
// ---------------------------------------------------------------------------
__global__ __launch_bounds__(256)
void scan_kernel(const float* __restrict__ u, const float* __restrict__ delta,
                 const float* __restrict__ xdbl,
                 const float* __restrict__ Alf, const float* __restrict__ Alb,
                 const float* __restrict__ Df, const float* __restrict__ Db,
                 float* __restrict__ y)
{
    const int n  = threadIdx.x & 15;
    const int dg = threadIdx.x >> 4;
    const int d  = blockIdx.x * 16 + dg;
    const int b = blockIdx.y, dir = blockIdx.z;
    const int dirb = dir * 2 + b;
    const float An2 = -expf((dir ? Alb : Alf)[d * 16 + n]) * 1.44269504f;
    const float Dd  = (dir ? Db : Df)[d];
    const float* up = u     + ((long)dirb * 2048 + d) * 1024;
    const float* dp = delta + ((long)dirb * 2048 + d) * 1024;
    const float* Bp = xdbl  + ((long)dirb * 96 + 64 + n) * 1024;
    const float* Cp = xdbl  + ((long)dirb * 96 + 80 + n) * 1024;
    float* yp = y + ((long)dirb * 2048 + d) * 1024;

    float h = 0.f;
    const bool wlane = (n == 0);
    for (int l0 = 0; l0 < 1024; l0 += 8) {
        f32x4 vD0 = *(const f32x4*)(dp + l0);
        f32x4 vD1 = *(const f32x4*)(dp + l0 + 4);
        f32x4 vU0 = *(const f32x4*)(up + l0);
        f32x4 vU1 = *(const f32x4*)(up + l0 + 4);
        f32x4 vB0 = *(const f32x4*)(Bp + l0);
        f32x4 vB1 = *(const f32x4*)(Bp + l0 + 4);
        f32x4 vC0 = *(const f32x4*)(Cp + l0);
        f32x4 vC1 = *(const f32x4*)(Cp + l0 + 4);
        float dls[8] = {vD0.x, vD0.y, vD0.z, vD0.w, vD1.x, vD1.y, vD1.z, vD1.w};
        float uus[8] = {vU0.x, vU0.y, vU0.z, vU0.w, vU1.x, vU1.y, vU1.z, vU1.w};
        float bbs[8] = {vB0.x, vB0.y, vB0.z, vB0.w, vB1.x, vB1.y, vB1.z, vB1.w};
        float ccs[8] = {vC0.x, vC0.y, vC0.z, vC0.w, vC1.x, vC1.y, vC1.z, vC1.w};
        float fy[8];
#pragma unroll
        for (int k = 0; k < 8; ++k) {
            float dA = __builtin_amdgcn_exp2f(dls[k] * An2);
            h = fmaf(dA, h, dls[k] * uus[k] * bbs[k]);
            float yc = h * ccs[k];
            yc = dpp_add<0xB1>(yc);    // quad_perm xor1
            yc = dpp_add<0x4E>(yc);    // quad_perm xor2
            yc = dpp_add<0x141>(yc);   // row_half_mirror
            yc = dpp_add<0x140>(yc);   // row_mirror -> full sum, all lanes
            fy[k] = fmaf(Dd, uus[k], yc);
        }
        if (wlane) {
            *(f32x4*)(yp + l0)     = (f32x4){fy[0], fy[1], fy[2], fy[3]};
            *(f32x4*)(yp + l0 + 4) = (f32x4){fy[4], fy[5], fy[6], fy[7]};
        }
    }
}

// G = silu(z) * (y_f + rev y_b), written TRANSPOSED as fp16 GT[b][l][d].
__global__ __launch_bounds__(256)
void combine_T_kernel(const float* __restrict__ xz, const float* __restrict__ y,
                      _Float16* __restrict__ GT)
{
    __shared__ float Ls[64][65];
    const int d0 = blockIdx.x * 64, l0 = blockIdx.y * 64, b = blockIdx.z;
    const int t = threadIdx.x;
#pragma unroll
    for (int rep = 0; rep < 4; ++rep) {
        int i = rep * 256 + t;
        int dl = i >> 4;
        int lq = (i & 15) * 4;
        const float* zp  = xz + ((long)b * 4096 + 2048 + d0 + dl) * 1024 + l0 + lq;
        const float* yfp = y  + ((long)(b)     * 2048 + d0 + dl) * 1024 + l0 + lq;
        const float* ybp = y  + ((long)(2 + b) * 2048 + d0 + dl) * 1024 + (1020 - l0 - lq);
        float4 vz = *(const float4*)zp;
        float4 vf = *(const float4*)yfp;
        float4 vb = *(const float4*)ybp;
        float zz[4]  = {vz.x, vz.y, vz.z, vz.w};
        float ff[4]  = {vf.x, vf.y, vf.z, vf.w};
        float bbv[4] = {vb.w, vb.z, vb.y, vb.x};   // reversed
#pragma unroll
        for (int qq = 0; qq < 4; ++qq) {
            float z = zz[qq];
            float sz = z / (1.f + __builtin_amdgcn_exp2f(-z * 1.44269504f));
            Ls[dl][lq + qq] = sz * (ff[qq] + bbv[qq]);
        }
    }
    __syncthreads();
#pragma unroll
    for (int rep = 0; rep < 4; ++rep) {
        int i = rep * 256 + t;
        int ll = i >> 4;
        int dq = (i & 15) * 4;
        f16x4 h = {(_Float16)Ls[dq][ll], (_Float16)Ls[dq + 1][ll],
                   (_Float16)Ls[dq + 2][ll], (_Float16)Ls[dq + 3][ll]};
        *(f16x4*)(GT + ((long)(b * 1024 + l0 + ll)) * 2048 + d0 + dq) = h;
    }
}

extern "C" void kernel_launch(void* const* d_in, const int* in_sizes, int n_in,
                              void* d_out, int out_size, void* d_ws, size_t ws_size,
                              hipStream_t stream)
{
    const float* hidden   = (const float*)d_in[0];
    const float* inproj_w = (const float*)d_in[1];
    const float* conv_w   = (const float*)d_in[2];
    const float* conv_b   = (const float*)d_in[3];
    const float* xproj_w  = (const float*)d_in[4];
    const float* dtproj_w = (const float*)d_in[5];
    const float* dt_bias  = (const float*)d_in[6];
    const float* A_log    = (const float*)d_in[7];
    const float* D_skip   = (const float*)d_in[8];
    const float* convb_w  = (const float*)d_in[9];
    const float* convb_b  = (const float*)d_in[10];
    const float* xprojb_w = (const float*)d_in[11];
    const float* dtprojb_w= (const float*)d_in[12];
    const float* dtb_bias = (const float*)d_in[13];
    const float* Ab_log   = (const float*)d_in[14];
    const float* Db_skip  = (const float*)d_in[15];
    const float* outproj_w= (const float*)d_in[16];
    float* out = (float*)d_out;

    float* ws    = (float*)d_ws;
    float* xz    = ws;
    float* u     = ws + 8388608;
    float* xdbl  = ws + 16777216;
    float* delta = ws + 17170432;
    float* y     = ws + 25559040;
    // fp16 aliases in temporally-dead regions:
    _Float16* H16    = (_Float16*)u;                 // 4 MB, dead before conv
    _Float16* Win16  = (_Float16*)(u + 1048576);     // 8 MB, dead before conv
    float*    xpb    = delta;                        // x_proj partials
    _Float16* GT     = (_Float16*)delta;             // after scan
    _Float16* Wout16 = (_Float16*)y;                 // after combine
    // scratch in y head (dead until scan writes y)
    _Float16* dw16   = (_Float16*)y;                 // 262144 fp16 = 131072 f32
    float*    bcat   = y + 131072;                   // 4096
    _Float16* xw16   = (_Float16*)(y + 135168);      // 393216 fp16 = 196608 f32

    // 0) f32 -> fp16 conversions (into dead u-region head)
    hipLaunchKernelGGL(cvt_f16_kernel, dim3(2048), dim3(256), 0, stream,
        hidden, H16, 2097152);
    hipLaunchKernelGGL(cvt_f16_kernel, dim3(4096), dim3(256), 0, stream,
        inproj_w, Win16, 4194304);

    // 0b) concat x_proj(fp16) / dt_proj(fp16) weights + dt bias(f32)
    hipLaunchKernelGGL(concat_weights, dim3(768), dim3(256), 0, stream,
        xproj_w, xprojb_w, dtproj_w, dtprojb_w, dt_bias, dtb_bias,
        xw16, dw16, bcat);

    // 1) in_proj MFMA: xz[b][e][l]
    hipLaunchKernelGGL((gemm_nt_f16<2, 2, 4, 4>),
        dim3(32, 8, 2), dim3(256), 0, stream,
        H16, Win16, xz, 1024, 1024, 1048576L, 4194304L);

    // 2) conv + silu (overwrites u region incl. H16/Win16)
    hipLaunchKernelGGL(conv_silu_kernel, dim3(32768), dim3(256), 0, stream,
        xz, conv_w, conv_b, convb_w, convb_b, u);

    // 3) x_proj MFMA split-K -> partials in delta region, then reduce
    hipLaunchKernelGGL(xproj_f16_kernel, dim3(8, XP_SK, 4), dim3(256), 0, stream,
        u, xw16, xpb);
    hipLaunchKernelGGL(xreduce_kernel, dim3(384), dim3(256), 0, stream,
        xpb, xdbl);

    // 4) dt_proj fp16 MFMA + softplus epilogue (overwrites partials)
    hipLaunchKernelGGL(dtproj_f16_kernel, dim3(16, 8, 4), dim3(256), 0, stream,
        xdbl, dw16, bcat, delta);

    // 5) fused selective scan v2
    hipLaunchKernelGGL(scan_kernel, dim3(128, 2, 2), dim3(256), 0, stream,
        u, delta, xdbl, A_log, Ab_log, D_skip, Db_skip, y);

    // 6) combine -> GT fp16 [b][l][d]
    hipLaunchKernelGGL(combine_T_kernel, dim3(32, 16, 2), dim3(256), 0, stream,
        xz, y, GT);

    // 7) W_out -> fp16 (into y head, after combine consumed y)
    hipLaunchKernelGGL(cvt_f16_kernel, dim3(2048), dim3(256), 0, stream,
        outproj_w, Wout16, 2097152);

    // 8) out_proj MFMA: out[(b,l)][o]
    hipLaunchKernelGGL((gemm_nt_f16<4, 1, 2, 4>),
        dim3(32, 8, 1), dim3(256), 0, stream,
        Wout16, GT, out, 2048, 1024, 0L, 0L);
}

// Round 10
// 224.674 us; speedup vs baseline: 1.2584x; 1.2584x over previous
//
#include <hip/hip_runtime.h>
#include <math.h>

// ---------------------------------------------------------------------------
// Bidirectional Mamba block, MI355X. Round 10:
//  - scan v3: 3-phase chunked scan. CH=8 chunks of 128 steps.
//    pass1: per-chunk local h_end + decay aprod=exp(A*sum(dl)) (log-trick).
//    pass2: sequential carry combine (tiny).
//    pass3: rescan from true h_init, emit y. Lanes = 16d x 4nl (4 states/lane):
//    4 exps + in-lane 4-fma reduce + 2 DPP quad adds per step; B/C staged
//    TRANSPOSED in LDS ([t][n]) for single ds_read_b128 per operand.
//    Carry buffers live in dead xz x-half rows (conv already consumed them).
//  - dt_proj fp16 MFMA kept (r9, verified: absmax unchanged).
//  - in/out_proj, x_proj MFMA, conv, combine unchanged (verified).
// ws layout (f32 elements):
//   xz    [b][4096][1024]   8,388,608  (x-half rows dead after conv:
//                                       hend @ +0 (1M), aprod @ +1M,
//                                       hinit @ +4194304 (1M))
//   u     [dirb][2048][1024] 8,388,608 (head: H16/Win16 before conv)
//   xdbl  [dirb][96][1024]     393,216
//   delta [dirb][2048][1024] 8,388,608 (head: x_proj partials; GT after scan)
//   y     [dirb][2048][1024] 8,388,608 (head: dw16/bcat/xw16; Wout16 later)
// ---------------------------------------------------------------------------

typedef _Float16 f16x8 __attribute__((ext_vector_type(8)));
typedef _Float16 f16x4 __attribute__((ext_vector_type(4)));
typedef float    f32x4 __attribute__((ext_vector_type(4)));

#define SCH 8     // scan chunks
#define SCL 128   // chunk length

__device__ __forceinline__ void gload_lds16(const void* g, void* l) {
    __builtin_amdgcn_global_load_lds(
        (const __attribute__((address_space(1))) void*)g,
        (__attribute__((address_space(3))) void*)l, 16, 0, 0);
}

__device__ __forceinline__ float softplus_f(float x) {
    float e = __builtin_amdgcn_exp2f(-fabsf(x) * 1.44269504f);
    return fmaxf(x, 0.f) + __builtin_amdgcn_logf(1.f + e) * 0.69314718f;
}

template<int CTRL>
__device__ __forceinline__ float dpp_add(float x) {
    int s = __builtin_amdgcn_update_dpp(0, __builtin_bit_cast(int, x),
                                        CTRL, 0xF, 0xF, true);
    return x + __builtin_bit_cast(float, s);
}

// ---------------------------------------------------------------------------
// fp16 NT MFMA GEMM (in_proj / out_proj)
// ---------------------------------------------------------------------------
template<int WMW, int WNW, int FM, int FN>
__global__ __launch_bounds__(256)
void gemm_nt_f16(const _Float16* __restrict__ A, const _Float16* __restrict__ B,
                 float* __restrict__ C, int K, int ldc, long sA, long sC)
{
    constexpr int BM = WMW * FM * 16, BN = WNW * FN * 16;
    constexpr int ACH = BM / 8, NCH = (BM + BN) / 8;
    __shared__ __align__(16) _Float16 lds[(BM + BN) * 64];
    A += (long)blockIdx.z * sA;
    C += (long)blockIdx.z * sC;
    const int m0 = blockIdx.y * BM, n0 = blockIdx.x * BN;
    const int t = threadIdx.x, wid = t >> 6, lane = t & 63;
    const int wm = wid / WNW, wn = wid % WNW;
    const int srow = lane >> 3;
    const int skk  = ((lane & 7) ^ srow) * 8;

    f32x4 acc[FM][FN];
#pragma unroll
    for (int i = 0; i < FM; ++i)
#pragma unroll
        for (int j = 0; j < FN; ++j) acc[i][j] = (f32x4){0.f, 0.f, 0.f, 0.f};

    for (int k0 = 0; k0 < K; k0 += 64) {
#pragma unroll
        for (int c = wid; c < NCH; c += 4) {
            const _Float16* gp = (c < ACH)
                ? A + (long)(m0 + c * 8 + srow) * K + k0 + skk
                : B + (long)(n0 + (c - ACH) * 8 + srow) * K + k0 + skk;
            gload_lds16(gp, lds + c * 512);
        }
        __syncthreads();
#pragma unroll
        for (int kw = 0; kw < 2; ++kw) {
            f16x8 af[FM], bf[FN];
#pragma unroll
            for (int i = 0; i < FM; ++i) {
                int r = wm * FM * 16 + i * 16 + (lane & 15);
                af[i] = *(const f16x8*)(lds + r * 64 +
                        (((kw * 4 + (lane >> 4)) ^ (r & 7)) * 8));
            }
#pragma unroll
            for (int j = 0; j < FN; ++j) {
                int r = wn * FN * 16 + j * 16 + (lane & 15);
                bf[j] = *(const f16x8*)(lds + BM * 64 + r * 64 +
                        (((kw * 4 + (lane >> 4)) ^ (r & 7)) * 8));
            }
#pragma unroll
            for (int i = 0; i < FM; ++i)
#pragma unroll
                for (int j = 0; j < FN; ++j)
                    acc[i][j] = __builtin_amdgcn_mfma_f32_16x16x32_f16(
                        af[i], bf[j], acc[i][j], 0, 0, 0);
        }
        __syncthreads();
    }
#pragma unroll
    for (int i = 0; i < FM; ++i)
#pragma unroll
        for (int j = 0; j < FN; ++j) {
            int n = n0 + wn * FN * 16 + j * 16 + (lane & 15);
            int m = m0 + wm * FM * 16 + i * 16 + (lane >> 4) * 4;
            *(f32x4*)&C[(long)n * ldc + m] = acc[i][j];
        }
}

// ---------------------------------------------------------------------------
// x_proj fp16 MFMA, split-K (verified r8)
// ---------------------------------------------------------------------------
#define XP_SK 8
__global__ __launch_bounds__(256)
void xproj_f16_kernel(const float* __restrict__ u, const _Float16* __restrict__ xw16,
                      float* __restrict__ pb)
{
    __shared__ __align__(16) _Float16 Asw[128 * 64];
    __shared__ __align__(16) _Float16 Bsw[96 * 64];
    const int t = threadIdx.x, wid = t >> 6, lane = t & 63;
    const int wm = wid >> 1, wn = wid & 1;
    const int m0 = blockIdx.x * 128;
    const int sk = blockIdx.y, dirb = blockIdx.z;
    const float* ub = u + (long)dirb * 2048 * 1024;
    const _Float16* Bw = xw16 + (long)(dirb >> 1) * 96 * 2048;
    const int srow = lane >> 3;
    const int skk  = ((lane & 7) ^ srow) * 8;
    const int lloc = (t & 31) * 4;
    const int kslt = t >> 5;

    f32x4 acc[4][3];
#pragma unroll
    for (int i = 0; i < 4; ++i)
#pragma unroll
        for (int j = 0; j < 3; ++j) acc[i][j] = (f32x4){0.f, 0.f, 0.f, 0.f};

    for (int ks = 0; ks < 2048 / XP_SK; ks += 64) {
        const int k0 = sk * (2048 / XP_SK) + ks;
#pragma unroll
        for (int c = wid; c < 12; c += 4)
            gload_lds16(Bw + (long)(c * 8 + srow) * 2048 + k0 + skk, Bsw + c * 512);
        float av[8][4];
#pragma unroll
        for (int kk = 0; kk < 8; ++kk) {
            f32x4 v = *(const f32x4*)&ub[(long)(k0 + kslt * 8 + kk) * 1024 + m0 + lloc];
            av[kk][0] = v.x; av[kk][1] = v.y; av[kk][2] = v.z; av[kk][3] = v.w;
        }
#pragma unroll
        for (int q = 0; q < 4; ++q) {
            int l = lloc + q;
            f16x8 h = {(_Float16)av[0][q], (_Float16)av[1][q], (_Float16)av[2][q],
                       (_Float16)av[3][q], (_Float16)av[4][q], (_Float16)av[5][q],
                       (_Float16)av[6][q], (_Float16)av[7][q]};
            *(f16x8*)(Asw + l * 64 + ((kslt ^ (l & 7)) * 8)) = h;
        }
        __syncthreads();
#pragma unroll
        for (int kw = 0; kw < 2; ++kw) {
            f16x8 af[4], bf[3];
#pragma unroll
            for (int i = 0; i < 4; ++i) {
                int r = wm * 64 + i * 16 + (lane & 15);
                af[i] = *(const f16x8*)(Asw + r * 64 +
                        (((kw * 4 + (lane >> 4)) ^ (r & 7)) * 8));
            }
#pragma unroll
            for (int j = 0; j < 3; ++j) {
                int r = wn * 48 + j * 16 + (lane & 15);
                bf[j] = *(const f16x8*)(Bsw + r * 64 +
                        (((kw * 4 + (lane >> 4)) ^ (r & 7)) * 8));
            }
#pragma unroll
            for (int i = 0; i < 4; ++i)
#pragma unroll
                for (int j = 0; j < 3; ++j)
                    acc[i][j] = __builtin_amdgcn_mfma_f32_16x16x32_f16(
                        af[i], bf[j], acc[i][j], 0, 0, 0);
        }
        __syncthreads();
    }
    float* Cp = pb + ((long)sk * 4 + dirb) * 96 * 1024;
#pragma unroll
    for (int i = 0; i < 4; ++i)
#pragma unroll
        for (int j = 0; j < 3; ++j) {
            int n = wn * 48 + j * 16 + (lane & 15);
            int m = m0 + wm * 64 + i * 16 + (lane >> 4) * 4;
            *(f32x4*)&Cp[(long)n * 1024 + m] = acc[i][j];
        }
}

__global__ __launch_bounds__(256)
void xreduce_kernel(const float* __restrict__ pb, float* __restrict__ xdbl)
{
    int f = (blockIdx.x * 256 + threadIdx.x) * 4;
    f32x4 s = (f32x4){0.f, 0.f, 0.f, 0.f};
#pragma unroll
    for (int sk = 0; sk < XP_SK; ++sk)
        s += *(const f32x4*)(pb + (long)sk * 393216 + f);
    *(f32x4*)(xdbl + f) = s;
}

// ---------------------------------------------------------------------------
// dt_proj fp16 MFMA + softplus epilogue (verified r9)
// ---------------------------------------------------------------------------
__global__ __launch_bounds__(256)
void dtproj_f16_kernel(const float* __restrict__ xdbl, const _Float16* __restrict__ dw16,
                       const float* __restrict__ bcat, float* __restrict__ delta)
{
    __shared__ __align__(16) _Float16 Asw[128 * 64];
    __shared__ __align__(16) _Float16 Bsw[128 * 64];
    const int t = threadIdx.x, wid = t >> 6, lane = t & 63;
    const int wm = wid >> 1, wn = wid & 1;
    const int n0 = blockIdx.x * 128, m0 = blockIdx.y * 128;
    const int dirb = blockIdx.z, dir = dirb >> 1;
    const float* Xb = xdbl + (long)dirb * 96 * 1024;
    const _Float16* Bw = dw16 + (long)dir * 2048 * 64;
    const int srow = lane >> 3, skk = ((lane & 7) ^ srow) * 8;
    const int lloc = (t & 31) * 4, kslt = t >> 5;

#pragma unroll
    for (int c = wid; c < 16; c += 4)
        gload_lds16(Bw + (long)(n0 + c * 8 + srow) * 64 + skk, Bsw + c * 512);
    float av[8][4];
#pragma unroll
    for (int kk = 0; kk < 8; ++kk) {
        f32x4 v = *(const f32x4*)&Xb[(long)(kslt * 8 + kk) * 1024 + m0 + lloc];
        av[kk][0] = v.x; av[kk][1] = v.y; av[kk][2] = v.z; av[kk][3] = v.w;
    }
#pragma unroll
    for (int q = 0; q < 4; ++q) {
        int l = lloc + q;
        f16x8 h = {(_Float16)av[0][q], (_Float16)av[1][q], (_Float16)av[2][q],
                   (_Float16)av[3][q], (_Float16)av[4][q], (_Float16)av[5][q],
                   (_Float16)av[6][q], (_Float16)av[7][q]};
        *(f16x8*)(Asw + l * 64 + ((kslt ^ (l & 7)) * 8)) = h;
    }
    __syncthreads();

    f32x4 acc[4][4];
#pragma unroll
    for (int i = 0; i < 4; ++i)
#pragma unroll
        for (int j = 0; j < 4; ++j) acc[i][j] = (f32x4){0.f, 0.f, 0.f, 0.f};
#pragma unroll
    for (int kw = 0; kw < 2; ++kw) {
        f16x8 af[4], bf[4];
#pragma unroll
        for (int i = 0; i < 4; ++i) {
            int r = wm * 64 + i * 16 + (lane & 15);
            af[i] = *(const f16x8*)(Asw + r * 64 +
                    (((kw * 4 + (lane >> 4)) ^ (r & 7)) * 8));
        }
#pragma unroll
        for (int j = 0; j < 4; ++j) {
            int r = wn * 64 + j * 16 + (lane & 15);
            bf[j] = *(const f16x8*)(Bsw + r * 64 +
                    (((kw * 4 + (lane >> 4)) ^ (r & 7)) * 8));
        }
#pragma unroll
        for (int i = 0; i < 4; ++i)
#pragma unroll
            for (int j = 0; j < 4; ++j)
                acc[i][j] = __builtin_amdgcn_mfma_f32_16x16x32_f16(
                    af[i], bf[j], acc[i][j], 0, 0, 0);
    }
    float* Dp = delta + (long)dirb * 2048 * 1024;
#pragma unroll
    for (int j = 0; j < 4; ++j) {
        int dd = n0 + wn * 64 + j * 16 + (lane & 15);
        float bm = bcat[dir * 2048 + dd];
#pragma unroll
        for (int i = 0; i < 4; ++i) {
            int m = m0 + wm * 64 + i * 16 + (lane >> 4) * 4;
            f32x4 v = acc[i][j];
            f32x4 o = {softplus_f(v.x + bm), softplus_f(v.y + bm),
                       softplus_f(v.z + bm), softplus_f(v.w + bm)};
            *(f32x4*)&Dp[(long)dd * 1024 + m] = o;
        }
    }
}

// f32 -> fp16 elementwise
__global__ __launch_bounds__(256)
void cvt_f16_kernel(const float* __restrict__ in, _Float16* __restrict__ out, int n)
{
    int i = (blockIdx.x * 256 + threadIdx.x) * 4;
    if (i + 3 < n) {
        float4 v = *(const float4*)(in + i);
        f16x4 h = {(_Float16)v.x, (_Float16)v.y, (_Float16)v.z, (_Float16)v.w};
        *(f16x4*)(out + i) = h;
    }
}

__global__ __launch_bounds__(256)
void concat_weights(const float* __restrict__ xwf, const float* __restrict__ xwb,
                    const float* __restrict__ dwf, const float* __restrict__ dwb,
                    const float* __restrict__ bf,  const float* __restrict__ bb,
                    _Float16* __restrict__ xw16, _Float16* __restrict__ dw16,
                    float* __restrict__ bcat)
{
    int i = blockIdx.x * 256 + threadIdx.x;
    if (i < 196608) { xw16[i] = (_Float16)xwf[i]; xw16[196608 + i] = (_Float16)xwb[i]; }
    if (i < 131072) { dw16[i] = (_Float16)dwf[i]; dw16[131072 + i] = (_Float16)dwb[i]; }
    if (i < 2048)   { bcat[i]  = bf[i];  bcat[2048 + i] = bb[i]; }
}

// Depthwise causal conv (k=4) + SiLU, both directions (bwd in reversed coords).
__global__ __launch_bounds__(256)
void conv_silu_kernel(const float* __restrict__ xz,
                      const float* __restrict__ wf, const float* __restrict__ bf,
                      const float* __restrict__ wb, const float* __restrict__ bbk,
                      float* __restrict__ u)
{
    long idx = (long)blockIdx.x * 256 + threadIdx.x;
    int l = (int)(idx & 1023);
    long r = idx >> 10;
    int d = (int)(r & 2047);
    int b = (int)((r >> 11) & 1);
    int dir = (int)(r >> 12);
    const float* x = xz + ((long)b * 4096 + d) * 1024;
    const float* w = dir ? wb : wf;
    float s = dir ? bbk[d] : bf[d];
    if (dir == 0) {
#pragma unroll
        for (int j = 0; j < 4; ++j) {
            int p = l - 3 + j;
            if (p >= 0) s = fmaf(w[d * 4 + j], x[p], s);
        }
    } else {
#pragma unroll
        for (int j = 0; j < 4; ++j) {
            int src = l - 3 + j;
            if (src >= 0) s = fmaf(w[d * 4 + j], x[1023 - src], s);
        }
    }
    u[idx] = s / (1.f + __builtin_amdgcn_exp2f(-s * 1.44269504f));
}

// ---------------------------------------------------------------------------
// scan v3 pass 1: per-chunk local scan (no y). Block = 4 waves x (16d x 4nl).
// Each lane holds 4 states. Outputs h_end[dirb][ch][d][16] and
// aprod[dirb][ch][d][16] = exp2(An2 * sum(dl)).
// ---------------------------------------------------------------------------
__global__ __launch_bounds__(256)
void scan_p1_kernel(const float* __restrict__ u, const float* __restrict__ delta,
                    const float* __restrict__ xdbl,
                    const float* __restrict__ Alf, const float* __restrict__ Alb,
                    float* __restrict__ hend, float* __restrict__ aprod)
{
    __shared__ float sD[64][36], sU[64][36], sB[32][20];
    const int t = threadIdx.x, wid = t >> 6, lane = t & 63;
    const int nl = lane & 3;
    const int dloc = wid * 16 + (lane >> 2);
    const int dblk = blockIdx.x, chunk = blockIdx.y, dirb = blockIdx.z;
    const int d = dblk * 64 + dloc, dir = dirb >> 1;
    const int T0 = chunk * SCL;
    f32x4 Av = *(const f32x4*)((dir ? Alb : Alf) + d * 16 + nl * 4);
    float An2[4] = {-expf(Av.x) * 1.44269504f, -expf(Av.y) * 1.44269504f,
                    -expf(Av.z) * 1.44269504f, -expf(Av.w) * 1.44269504f};
    const float* dp = delta + ((long)dirb * 2048 + dblk * 64) * 1024;
    const float* up = u     + ((long)dirb * 2048 + dblk * 64) * 1024;
    const float* Bp = xdbl  + ((long)dirb * 96 + 64) * 1024;

    float h[4] = {0.f, 0.f, 0.f, 0.f};
    float S = 0.f;
    for (int tile = 0; tile < SCL / 32; ++tile) {
        const int t0 = T0 + tile * 32;
#pragma unroll
        for (int rep = 0; rep < 2; ++rep) {
            int ii = rep * 256 + t;
            int dd = ii >> 3, q = ii & 7;
            *(f32x4*)&sD[dd][q * 4] = *(const f32x4*)&dp[(long)dd * 1024 + t0 + q * 4];
            *(f32x4*)&sU[dd][q * 4] = *(const f32x4*)&up[(long)dd * 1024 + t0 + q * 4];
        }
#pragma unroll
        for (int rep = 0; rep < 2; ++rep) {
            int ii = rep * 256 + t;
            int n = ii >> 5, tt = ii & 31;
            sB[tt][n] = Bp[(long)n * 1024 + t0 + tt];
        }
        __syncthreads();
#pragma unroll
        for (int g = 0; g < 8; ++g) {
            f32x4 dlv = *(const f32x4*)&sD[dloc][g * 4];
            f32x4 uuv = *(const f32x4*)&sU[dloc][g * 4];
            float dls[4] = {dlv.x, dlv.y, dlv.z, dlv.w};
            float uus[4] = {uuv.x, uuv.y, uuv.z, uuv.w};
#pragma unroll
            for (int r4 = 0; r4 < 4; ++r4) {
                f32x4 Bv = *(const f32x4*)&sB[g * 4 + r4][nl * 4];
                float Bs[4] = {Bv.x, Bv.y, Bv.z, Bv.w};
                float dl = dls[r4], t1 = dl * uus[r4];
                S += dl;
#pragma unroll
                for (int r = 0; r < 4; ++r)
                    h[r] = fmaf(__builtin_amdgcn_exp2f(dl * An2[r]), h[r], t1 * Bs[r]);
            }
        }
        __syncthreads();
    }
    long cb = (((long)dirb * SCH + chunk) * 2048 + d) * 16 + nl * 4;
    *(f32x4*)&hend[cb]  = (f32x4){h[0], h[1], h[2], h[3]};
    *(f32x4*)&aprod[cb] = (f32x4){__builtin_amdgcn_exp2f(S * An2[0]),
                                  __builtin_amdgcn_exp2f(S * An2[1]),
                                  __builtin_amdgcn_exp2f(S * An2[2]),
                                  __builtin_amdgcn_exp2f(S * An2[3])};
}

// scan v3 pass 2: sequential carry combine. hinit[c] = true state before chunk c.
__global__ __launch_bounds__(256)
void scan_carry_kernel(const float* __restrict__ hend, const float* __restrict__ aprod,
                       float* __restrict__ hinit)
{
    int f = blockIdx.x * 256 + threadIdx.x;   // (dirb, d*16+n)
    int dn = f & 32767;
    int dirb = f >> 15;
    long base = (long)dirb * SCH * 32768 + dn;
    float hcur = 0.f;
#pragma unroll
    for (int c = 0; c < SCH; ++c) {
        hinit[base + (long)c * 32768] = hcur;
        hcur = hend[base + (long)c * 32768]
             + aprod[base + (long)c * 32768] * hcur;
    }
}

// scan v3 pass 3: full scan per chunk from hinit, emitting y.
__global__ __launch_bounds__(256)
void scan_p3_kernel(const float* __restrict__ u, const float* __restrict__ delta,
                    const float* __restrict__ xdbl,
                    const float* __restrict__ Alf, const float* __restrict__ Alb,
                    const float* __restrict__ Df, const float* __restrict__ Db,
                    const float* __restrict__ hinit, float* __restrict__ y)
{
    __shared__ float sD[64][36], sU[64][36], sB[32][20], sC[32][20];
    const int t = threadIdx.x, wid = t >> 6, lane = t & 63;
    const int nl = lane & 3;
    const int dloc = wid * 16 + (lane >> 2);
    const int dblk = blockIdx.x, chunk = blockIdx.y, dirb = blockIdx.z;
    const int d = dblk * 64 + dloc, dir = dirb >> 1;
    const int T0 = chunk * SCL;
    f32x4 Av = *(const f32x4*)((dir ? Alb : Alf) + d * 16 + nl * 4);
    float An2[4] = {-expf(Av.x) * 1.44269504f, -expf(Av.y) * 1.44269504f,
                    -expf(Av.z) * 1.44269504f, -expf(Av.w) * 1.44269504f};
    const float Dd = (dir ? Db : Df)[d];
    const float* dp = delta + ((long)dirb * 2048 + dblk * 64) * 1024;
    const float* up = u     + ((long)dirb * 2048 + dblk * 64) * 1024;
    const float* Bp = xdbl  + ((long)dirb * 96 + 64) * 1024;
    const float* Cp = xdbl  + ((long)dirb * 96 + 80) * 1024;
    float* yrow = y + ((long)dirb * 2048 + d) * 1024;

    long cb = (((long)dirb * SCH + chunk) * 2048 + d) * 16 + nl * 4;
    f32x4 h0v = *(const f32x4*)&hinit[cb];
    float h[4] = {h0v.x, h0v.y, h0v.z, h0v.w};
    const bool m[4] = {nl == 0, nl == 1, nl == 2, nl == 3};

    for (int tile = 0; tile < SCL / 32; ++tile) {
        const int t0 = T0 + tile * 32;
#pragma unroll
        for (int rep = 0; rep < 2; ++rep) {
            int ii = rep * 256 + t;
            int dd = ii >> 3, q = ii & 7;
            *(f32x4*)&sD[dd][q * 4] = *(const f32x4*)&dp[(long)dd * 1024 + t0 + q * 4];
            *(f32x4*)&sU[dd][q * 4] = *(const f32x4*)&up[(long)dd * 1024 + t0 + q * 4];
        }
#pragma unroll
        for (int rep = 0; rep < 2; ++rep) {
            int ii = rep * 256 + t;
            int n = ii >> 5, tt = ii & 31;
            sB[tt][n] = Bp[(long)n * 1024 + t0 + tt];
            sC[tt][n] = Cp[(long)n * 1024 + t0 + tt];
        }
        __syncthreads();
#pragma unroll
        for (int g = 0; g < 8; ++g) {
            f32x4 dlv = *(const f32x4*)&sD[dloc][g * 4];
            f32x4 uuv = *(const f32x4*)&sU[dloc][g * 4];
            float dls[4] = {dlv.x, dlv.y, dlv.z, dlv.w};
            float uus[4] = {uuv.x, uuv.y, uuv.z, uuv.w};
            float keep = 0.f;
#pragma unroll
            for (int r4 = 0; r4 < 4; ++r4) {
                f32x4 Bv = *(const f32x4*)&sB[g * 4 + r4][nl * 4];
                f32x4 Cv = *(const f32x4*)&sC[g * 4 + r4][nl * 4];
                float Bs[4] = {Bv.x, Bv.y, Bv.z, Bv.w};
                float Cs[4] = {Cv.x, Cv.y, Cv.z, Cv.w};
                float dl = dls[r4], uu = uus[r4];
                float t1 = dl * uu;
#pragma unroll
                for (int r = 0; r < 4; ++r)
                    h[r] = fmaf(__builtin_amdgcn_exp2f(dl * An2[r]), h[r], t1 * Bs[r]);
                float p = h[0] * Cs[0];
                p = fmaf(h[1], Cs[1], p);
                p = fmaf(h[2], Cs[2], p);
                p = fmaf(h[3], Cs[3], p);
                p = dpp_add<0xB1>(p);      // quad xor1
                p = dpp_add<0x4E>(p);      // quad xor2 -> sum over 16 n, all 4 lanes
                float fy = fmaf(Dd, uu, p);
                keep = m[r4] ? fy : keep;
            }
            yrow[t0 + g * 4 + nl] = keep;
        }
        __syncthreads();
    }
}

// G = silu(z) * (y_f + rev y_b), written TRANSPOSED as fp16 GT[b][l][d].
__global__ __launch_bounds__(256)
void combine_T_kernel(const float* __restrict__ xz, const float* __restrict__ y,
                      _Float16* __restrict__ GT)
{
    __shared__ float Ls[64][65];
    const int d0 = blockIdx.x * 64, l0 = blockIdx.y * 64, b = blockIdx.z;
    const int t = threadIdx.x;
#pragma unroll
    for (int rep = 0; rep < 4; ++rep) {
        int i = rep * 256 + t;
        int dl = i >> 4;
        int lq = (i & 15) * 4;
        const float* zp  = xz + ((long)b * 4096 + 2048 + d0 + dl) * 1024 + l0 + lq;
        const float* yfp = y  + ((long)(b)     * 2048 + d0 + dl) * 1024 + l0 + lq;
        const float* ybp = y  + ((long)(2 + b) * 2048 + d0 + dl) * 1024 + (1020 - l0 - lq);
        float4 vz = *(const float4*)zp;
        float4 vf = *(const float4*)yfp;
        float4 vb = *(const float4*)ybp;
        float zz[4]  = {vz.x, vz.y, vz.z, vz.w};
        float ff[4]  = {vf.x, vf.y, vf.z, vf.w};
        float bbv[4] = {vb.w, vb.z, vb.y, vb.x};
#pragma unroll
        for (int qq = 0; qq < 4; ++qq) {
            float z = zz[qq];
            float sz = z / (1.f + __builtin_amdgcn_exp2f(-z * 1.44269504f));
            Ls[dl][lq + qq] = sz * (ff[qq] + bbv[qq]);
        }
    }
    __syncthreads();
#pragma unroll
    for (int rep = 0; rep < 4; ++rep) {
        int i = rep * 256 + t;
        int ll = i >> 4;
        int dq = (i & 15) * 4;
        f16x4 h = {(_Float16)Ls[dq][ll], (_Float16)Ls[dq + 1][ll],
                   (_Float16)Ls[dq + 2][ll], (_Float16)Ls[dq + 3][ll]};
        *(f16x4*)(GT + ((long)(b * 1024 + l0 + ll)) * 2048 + d0 + dq) = h;
    }
}

extern "C" void kernel_launch(void* const* d_in, const int* in_sizes, int n_in,
                              void* d_out, int out_size, void* d_ws, size_t ws_size,
                              hipStream_t stream)
{
    const float* hidden   = (const float*)d_in[0];
    const float* inproj_w = (const float*)d_in[1];
    const float* conv_w   = (const float*)d_in[2];
    const float* conv_b   = (const float*)d_in[3];
    const float* xproj_w  = (const float*)d_in[4];
    const float* dtproj_w = (const float*)d_in[5];
    const float* dt_bias  = (const float*)d_in[6];
    const float* A_log    = (const float*)d_in[7];
    const float* D_skip   = (const float*)d_in[8];
    const float* convb_w  = (const float*)d_in[9];
    const float* convb_b  = (const float*)d_in[10];
    const float* xprojb_w = (const float*)d_in[11];
    const float* dtprojb_w= (const float*)d_in[12];
    const float* dtb_bias = (const float*)d_in[13];
    const float* Ab_log   = (const float*)d_in[14];
    const float* Db_skip  = (const float*)d_in[15];
    const float* outproj_w= (const float*)d_in[16];
    float* out = (float*)d_out;

    float* ws    = (float*)d_ws;
    float* xz    = ws;
    float* u     = ws + 8388608;
    float* xdbl  = ws + 16777216;
    float* delta = ws + 17170432;
    float* y     = ws + 25559040;
    // fp16 / scratch aliases in temporally-dead regions:
    _Float16* H16    = (_Float16*)u;
    _Float16* Win16  = (_Float16*)(u + 1048576);
    float*    xpb    = delta;                       // x_proj partials
    _Float16* GT     = (_Float16*)delta;            // after scan
    _Float16* Wout16 = (_Float16*)y;                // after combine
    _Float16* dw16   = (_Float16*)y;                // pre-scan scratch
    float*    bcat   = y + 131072;
    _Float16* xw16   = (_Float16*)(y + 135168);
    // scan carry buffers in dead xz x-half rows (conv consumed them):
    float* hend  = xz;                              // 1,048,576
    float* aprod = xz + 1048576;                    // 1,048,576
    float* hinit = xz + 4194304;                    // 1,048,576 (b=1 x-half)

    // 0) f32 -> fp16 conversions
    hipLaunchKernelGGL(cvt_f16_kernel, dim3(2048), dim3(256), 0, stream,
        hidden, H16, 2097152);
    hipLaunchKernelGGL(cvt_f16_kernel, dim3(4096), dim3(256), 0, stream,
        inproj_w, Win16, 4194304);

    // 0b) weight concat/convert
    hipLaunchKernelGGL(concat_weights, dim3(768), dim3(256), 0, stream,
        xproj_w, xprojb_w, dtproj_w, dtprojb_w, dt_bias, dtb_bias,
        xw16, dw16, bcat);

    // 1) in_proj MFMA
    hipLaunchKernelGGL((gemm_nt_f16<2, 2, 4, 4>),
        dim3(32, 8, 2), dim3(256), 0, stream,
        H16, Win16, xz, 1024, 1024, 1048576L, 4194304L);

    // 2) conv + silu
    hipLaunchKernelGGL(conv_silu_kernel, dim3(32768), dim3(256), 0, stream,
        xz, conv_w, conv_b, convb_w, convb_b, u);

    // 3) x_proj MFMA split-K + reduce
    hipLaunchKernelGGL(xproj_f16_kernel, dim3(8, XP_SK, 4), dim3(256), 0, stream,
        u, xw16, xpb);
    hipLaunchKernelGGL(xreduce_kernel, dim3(384), dim3(256), 0, stream,
        xpb, xdbl);

    // 4) dt_proj fp16 MFMA + softplus
    hipLaunchKernelGGL(dtproj_f16_kernel, dim3(16, 8, 4), dim3(256), 0, stream,
        xdbl, dw16, bcat, delta);

    // 5) scan v3: pass1 (local scans) -> carry -> pass3 (emit y)
    hipLaunchKernelGGL(scan_p1_kernel, dim3(32, SCH, 4), dim3(256), 0, stream,
        u, delta, xdbl, A_log, Ab_log, hend, aprod);
    hipLaunchKernelGGL(scan_carry_kernel, dim3(512), dim3(256), 0, stream,
        hend, aprod, hinit);
    hipLaunchKernelGGL(scan_p3_kernel, dim3(32, SCH, 4), dim3(256), 0, stream,
        u, delta, xdbl, A_log, Ab_log, D_skip, Db_skip, hinit, y);

    // 6) combine -> GT fp16
    hipLaunchKernelGGL(combine_T_kernel, dim3(32, 16, 2), dim3(256), 0, stream,
        xz, y, GT);

    // 7) W_out -> fp16
    hipLaunchKernelGGL(cvt_f16_kernel, dim3(2048), dim3(256), 0, stream,
        outproj_w, Wout16, 2097152);

    // 8) out_proj MFMA
    hipLaunchKernelGGL((gemm_nt_f16<4, 1, 2, 4>),
        dim3(32, 8, 1), dim3(256), 0, stream,
        Wout16, GT, out, 2048, 1024, 0L, 0L);
}

// Round 11
// 198.952 us; speedup vs baseline: 1.4211x; 1.1293x over previous
//
#include <hip/hip_runtime.h>
#include <math.h>

// ---------------------------------------------------------------------------
// Bidirectional Mamba block, MI355X. Round 11:
//  - scan v4: 3-phase chunked scan, SCH=16 chunks of SCL=64 steps.
//    Whole-chunk single-shot LDS staging (1 barrier/chunk), barrier-free
//    64-step inner loop, 2048 blocks/pass for occupancy.
//    Carry buffers: hend/aprod in y region (dead pre-p3), hinit in dead
//    xz b0 x-half.
//  - dt/x/in/out_proj MFMA, conv, combine unchanged (verified r10).
// ws layout (f32 elements):
//   xz    [b][4096][1024]   8,388,608  (b0 x-half [0,2M): hinit after conv)
//   u     [dirb][2048][1024] 8,388,608 (head: H16/Win16 before conv)
//   xdbl  [dirb][96][1024]     393,216
//   delta [dirb][2048][1024] 8,388,608 (head: x_proj partials; GT after scan)
//   y     [dirb][2048][1024] 8,388,608 (head: weights scratch -> hend@0,
//                                       aprod@2M during scan -> y by p3 ->
//                                       Wout16 after combine)
// ---------------------------------------------------------------------------

typedef _Float16 f16x8 __attribute__((ext_vector_type(8)));
typedef _Float16 f16x4 __attribute__((ext_vector_type(4)));
typedef float    f32x4 __attribute__((ext_vector_type(4)));

#define SCH 16    // scan chunks
#define SCL 64    // chunk length

__device__ __forceinline__ void gload_lds16(const void* g, void* l) {
    __builtin_amdgcn_global_load_lds(
        (const __attribute__((address_space(1))) void*)g,
        (__attribute__((address_space(3))) void*)l, 16, 0, 0);
}

__device__ __forceinline__ float softplus_f(float x) {
    float e = __builtin_amdgcn_exp2f(-fabsf(x) * 1.44269504f);
    return fmaxf(x, 0.f) + __builtin_amdgcn_logf(1.f + e) * 0.69314718f;
}

template<int CTRL>
__device__ __forceinline__ float dpp_add(float x) {
    int s = __builtin_amdgcn_update_dpp(0, __builtin_bit_cast(int, x),
                                        CTRL, 0xF, 0xF, true);
    return x + __builtin_bit_cast(float, s);
}

// ---------------------------------------------------------------------------
// fp16 NT MFMA GEMM (in_proj / out_proj)
// ---------------------------------------------------------------------------
template<int WMW, int WNW, int FM, int FN>
__global__ __launch_bounds__(256)
void gemm_nt_f16(const _Float16* __restrict__ A, const _Float16* __restrict__ B,
                 float* __restrict__ C, int K, int ldc, long sA, long sC)
{
    constexpr int BM = WMW * FM * 16, BN = WNW * FN * 16;
    constexpr int ACH = BM / 8, NCH = (BM + BN) / 8;
    __shared__ __align__(16) _Float16 lds[(BM + BN) * 64];
    A += (long)blockIdx.z * sA;
    C += (long)blockIdx.z * sC;
    const int m0 = blockIdx.y * BM, n0 = blockIdx.x * BN;
    const int t = threadIdx.x, wid = t >> 6, lane = t & 63;
    const int wm = wid / WNW, wn = wid % WNW;
    const int srow = lane >> 3;
    const int skk  = ((lane & 7) ^ srow) * 8;

    f32x4 acc[FM][FN];
#pragma unroll
    for (int i = 0; i < FM; ++i)
#pragma unroll
        for (int j = 0; j < FN; ++j) acc[i][j] = (f32x4){0.f, 0.f, 0.f, 0.f};

    for (int k0 = 0; k0 < K; k0 += 64) {
#pragma unroll
        for (int c = wid; c < NCH; c += 4) {
            const _Float16* gp = (c < ACH)
                ? A + (long)(m0 + c * 8 + srow) * K + k0 + skk
                : B + (long)(n0 + (c - ACH) * 8 + srow) * K + k0 + skk;
            gload_lds16(gp, lds + c * 512);
        }
        __syncthreads();
#pragma unroll
        for (int kw = 0; kw < 2; ++kw) {
            f16x8 af[FM], bf[FN];
#pragma unroll
            for (int i = 0; i < FM; ++i) {
                int r = wm * FM * 16 + i * 16 + (lane & 15);
                af[i] = *(const f16x8*)(lds + r * 64 +
                        (((kw * 4 + (lane >> 4)) ^ (r & 7)) * 8));
            }
#pragma unroll
            for (int j = 0; j < FN; ++j) {
                int r = wn * FN * 16 + j * 16 + (lane & 15);
                bf[j] = *(const f16x8*)(lds + BM * 64 + r * 64 +
                        (((kw * 4 + (lane >> 4)) ^ (r & 7)) * 8));
            }
#pragma unroll
            for (int i = 0; i < FM; ++i)
#pragma unroll
                for (int j = 0; j < FN; ++j)
                    acc[i][j] = __builtin_amdgcn_mfma_f32_16x16x32_f16(
                        af[i], bf[j], acc[i][j], 0, 0, 0);
        }
        __syncthreads();
    }
#pragma unroll
    for (int i = 0; i < FM; ++i)
#pragma unroll
        for (int j = 0; j < FN; ++j) {
            int n = n0 + wn * FN * 16 + j * 16 + (lane & 15);
            int m = m0 + wm * FM * 16 + i * 16 + (lane >> 4) * 4;
            *(f32x4*)&C[(long)n * ldc + m] = acc[i][j];
        }
}

// ---------------------------------------------------------------------------
// x_proj fp16 MFMA, split-K (verified r8)
// ---------------------------------------------------------------------------
#define XP_SK 8
__global__ __launch_bounds__(256)
void xproj_f16_kernel(const float* __restrict__ u, const _Float16* __restrict__ xw16,
                      float* __restrict__ pb)
{
    __shared__ __align__(16) _Float16 Asw[128 * 64];
    __shared__ __align__(16) _Float16 Bsw[96 * 64];
    const int t = threadIdx.x, wid = t >> 6, lane = t & 63;
    const int wm = wid >> 1, wn = wid & 1;
    const int m0 = blockIdx.x * 128;
    const int sk = blockIdx.y, dirb = blockIdx.z;
    const float* ub = u + (long)dirb * 2048 * 1024;
    const _Float16* Bw = xw16 + (long)(dirb >> 1) * 96 * 2048;
    const int srow = lane >> 3;
    const int skk  = ((lane & 7) ^ srow) * 8;
    const int lloc = (t & 31) * 4;
    const int kslt = t >> 5;

    f32x4 acc[4][3];
#pragma unroll
    for (int i = 0; i < 4; ++i)
#pragma unroll
        for (int j = 0; j < 3; ++j) acc[i][j] = (f32x4){0.f, 0.f, 0.f, 0.f};

    for (int ks = 0; ks < 2048 / XP_SK; ks += 64) {
        const int k0 = sk * (2048 / XP_SK) + ks;
#pragma unroll
        for (int c = wid; c < 12; c += 4)
            gload_lds16(Bw + (long)(c * 8 + srow) * 2048 + k0 + skk, Bsw + c * 512);
        float av[8][4];
#pragma unroll
        for (int kk = 0; kk < 8; ++kk) {
            f32x4 v = *(const f32x4*)&ub[(long)(k0 + kslt * 8 + kk) * 1024 + m0 + lloc];
            av[kk][0] = v.x; av[kk][1] = v.y; av[kk][2] = v.z; av[kk][3] = v.w;
        }
#pragma unroll
        for (int q = 0; q < 4; ++q) {
            int l = lloc + q;
            f16x8 h = {(_Float16)av[0][q], (_Float16)av[1][q], (_Float16)av[2][q],
                       (_Float16)av[3][q], (_Float16)av[4][q], (_Float16)av[5][q],
                       (_Float16)av[6][q], (_Float16)av[7][q]};
            *(f16x8*)(Asw + l * 64 + ((kslt ^ (l & 7)) * 8)) = h;
        }
        __syncthreads();
#pragma unroll
        for (int kw = 0; kw < 2; ++kw) {
            f16x8 af[4], bf[3];
#pragma unroll
            for (int i = 0; i < 4; ++i) {
                int r = wm * 64 + i * 16 + (lane & 15);
                af[i] = *(const f16x8*)(Asw + r * 64 +
                        (((kw * 4 + (lane >> 4)) ^ (r & 7)) * 8));
            }
#pragma unroll
            for (int j = 0; j < 3; ++j) {
                int r = wn * 48 + j * 16 + (lane & 15);
                bf[j] = *(const f16x8*)(Bsw + r * 64 +
                        (((kw * 4 + (lane >> 4)) ^ (r & 7)) * 8));
            }
#pragma unroll
            for (int i = 0; i < 4; ++i)
#pragma unroll
                for (int j = 0; j < 3; ++j)
                    acc[i][j] = __builtin_amdgcn_mfma_f32_16x16x32_f16(
                        af[i], bf[j], acc[i][j], 0, 0, 0);
        }
        __syncthreads();
    }
    float* Cp = pb + ((long)sk * 4 + dirb) * 96 * 1024;
#pragma unroll
    for (int i = 0; i < 4; ++i)
#pragma unroll
        for (int j = 0; j < 3; ++j) {
            int n = wn * 48 + j * 16 + (lane & 15);
            int m = m0 + wm * 64 + i * 16 + (lane >> 4) * 4;
            *(f32x4*)&Cp[(long)n * 1024 + m] = acc[i][j];
        }
}

__global__ __launch_bounds__(256)
void xreduce_kernel(const float* __restrict__ pb, float* __restrict__ xdbl)
{
    int f = (blockIdx.x * 256 + threadIdx.x) * 4;
    f32x4 s = (f32x4){0.f, 0.f, 0.f, 0.f};
#pragma unroll
    for (int sk = 0; sk < XP_SK; ++sk)
        s += *(const f32x4*)(pb + (long)sk * 393216 + f);
    *(f32x4*)(xdbl + f) = s;
}

// ---------------------------------------------------------------------------
// dt_proj fp16 MFMA + softplus epilogue (verified r9)
// ---------------------------------------------------------------------------
__global__ __launch_bounds__(256)
void dtproj_f16_kernel(const float* __restrict__ xdbl, const _Float16* __restrict__ dw16,
                       const float* __restrict__ bcat, float* __restrict__ delta)
{
    __shared__ __align__(16) _Float16 Asw[128 * 64];
    __shared__ __align__(16) _Float16 Bsw[128 * 64];
    const int t = threadIdx.x, wid = t >> 6, lane = t & 63;
    const int wm = wid >> 1, wn = wid & 1;
    const int n0 = blockIdx.x * 128, m0 = blockIdx.y * 128;
    const int dirb = blockIdx.z, dir = dirb >> 1;
    const float* Xb = xdbl + (long)dirb * 96 * 1024;
    const _Float16* Bw = dw16 + (long)dir * 2048 * 64;
    const int srow = lane >> 3, skk = ((lane & 7) ^ srow) * 8;
    const int lloc = (t & 31) * 4, kslt = t >> 5;

#pragma unroll
    for (int c = wid; c < 16; c += 4)
        gload_lds16(Bw + (long)(n0 + c * 8 + srow) * 64 + skk, Bsw + c * 512);
    float av[8][4];
#pragma unroll
    for (int kk = 0; kk < 8; ++kk) {
        f32x4 v = *(const f32x4*)&Xb[(long)(kslt * 8 + kk) * 1024 + m0 + lloc];
        av[kk][0] = v.x; av[kk][1] = v.y; av[kk][2] = v.z; av[kk][3] = v.w;
    }
#pragma unroll
    for (int q = 0; q < 4; ++q) {
        int l = lloc + q;
        f16x8 h = {(_Float16)av[0][q], (_Float16)av[1][q], (_Float16)av[2][q],
                   (_Float16)av[3][q], (_Float16)av[4][q], (_Float16)av[5][q],
                   (_Float16)av[6][q], (_Float16)av[7][q]};
        *(f16x8*)(Asw + l * 64 + ((kslt ^ (l & 7)) * 8)) = h;
    }
    __syncthreads();

    f32x4 acc[4][4];
#pragma unroll
    for (int i = 0; i < 4; ++i)
#pragma unroll
        for (int j = 0; j < 4; ++j) acc[i][j] = (f32x4){0.f, 0.f, 0.f, 0.f};
#pragma unroll
    for (int kw = 0; kw < 2; ++kw) {
        f16x8 af[4], bf[4];
#pragma unroll
        for (int i = 0; i < 4; ++i) {
            int r = wm * 64 + i * 16 + (lane & 15);
            af[i] = *(const f16x8*)(Asw + r * 64 +
                    (((kw * 4 + (lane >> 4)) ^ (r & 7)) * 8));
        }
#pragma unroll
        for (int j = 0; j < 4; ++j) {
            int r = wn * 64 + j * 16 + (lane & 15);
            bf[j] = *(const f16x8*)(Bsw + r * 64 +
                    (((kw * 4 + (lane >> 4)) ^ (r & 7)) * 8));
        }
#pragma unroll
        for (int i = 0; i < 4; ++i)
#pragma unroll
            for (int j = 0; j < 4; ++j)
                acc[i][j] = __builtin_amdgcn_mfma_f32_16x16x32_f16(
                    af[i], bf[j], acc[i][j], 0, 0, 0);
    }
    float* Dp = delta + (long)dirb * 2048 * 1024;
#pragma unroll
    for (int j = 0; j < 4; ++j) {
        int dd = n0 + wn * 64 + j * 16 + (lane & 15);
        float bm = bcat[dir * 2048 + dd];
#pragma unroll
        for (int i = 0; i < 4; ++i) {
            int m = m0 + wm * 64 + i * 16 + (lane >> 4) * 4;
            f32x4 v = acc[i][j];
            f32x4 o = {softplus_f(v.x + bm), softplus_f(v.y + bm),
                       softplus_f(v.z + bm), softplus_f(v.w + bm)};
            *(f32x4*)&Dp[(long)dd * 1024 + m] = o;
        }
    }
}

// f32 -> fp16 elementwise
__global__ __launch_bounds__(256)
void cvt_f16_kernel(const float* __restrict__ in, _Float16* __restrict__ out, int n)
{
    int i = (blockIdx.x * 256 + threadIdx.x) * 4;
    if (i + 3 < n) {
        float4 v = *(const float4*)(in + i);
        f16x4 h = {(_Float16)v.x, (_Float16)v.y, (_Float16)v.z, (_Float16)v.w};
        *(f16x4*)(out + i) = h;
    }
}

__global__ __launch_bounds__(256)
void concat_weights(const float* __restrict__ xwf, const float* __restrict__ xwb,
                    const float* __restrict__ dwf, const float* __restrict__ dwb,
                    const float* __restrict__ bf,  const float* __restrict__ bb,
                    _Float16* __restrict__ xw16, _Float16* __restrict__ dw16,
                    float* __restrict__ bcat)
{
    int i = blockIdx.x * 256 + threadIdx.x;
    if (i < 196608) { xw16[i] = (_Float16)xwf[i]; xw16[196608 + i] = (_Float16)xwb[i]; }
    if (i < 131072) { dw16[i] = (_Float16)dwf[i]; dw16[131072 + i] = (_Float16)dwb[i]; }
    if (i < 2048)   { bcat[i]  = bf[i];  bcat[2048 + i] = bb[i]; }
}

// Depthwise causal conv (k=4) + SiLU, both directions (bwd in reversed coords).
__global__ __launch_bounds__(256)
void conv_silu_kernel(const float* __restrict__ xz,
                      const float* __restrict__ wf, const float* __restrict__ bf,
                      const float* __restrict__ wb, const float* __restrict__ bbk,
                      float* __restrict__ u)
{
    long idx = (long)blockIdx.x * 256 + threadIdx.x;
    int l = (int)(idx & 1023);
    long r = idx >> 10;
    int d = (int)(r & 2047);
    int b = (int)((r >> 11) & 1);
    int dir = (int)(r >> 12);
    const float* x = xz + ((long)b * 4096 + d) * 1024;
    const float* w = dir ? wb : wf;
    float s = dir ? bbk[d] : bf[d];
    if (dir == 0) {
#pragma unroll
        for (int j = 0; j < 4; ++j) {
            int p = l - 3 + j;
            if (p >= 0) s = fmaf(w[d * 4 + j], x[p], s);
        }
    } else {
#pragma unroll
        for (int j = 0; j < 4; ++j) {
            int src = l - 3 + j;
            if (src >= 0) s = fmaf(w[d * 4 + j], x[1023 - src], s);
        }
    }
    u[idx] = s / (1.f + __builtin_amdgcn_exp2f(-s * 1.44269504f));
}

// ---------------------------------------------------------------------------
// scan v4 pass 1: per-chunk local scan. Block = 4 waves x (16d x 4nl),
// 64 d per block, SCL=64 steps staged whole-chunk (1 barrier).
// Outputs h_end and aprod = exp2(An2 * sum(dl)).
// ---------------------------------------------------------------------------
__global__ __launch_bounds__(256)
void scan_p1_kernel(const float* __restrict__ u, const float* __restrict__ delta,
                    const float* __restrict__ xdbl,
                    const float* __restrict__ Alf, const float* __restrict__ Alb,
                    float* __restrict__ hend, float* __restrict__ aprod)
{
    __shared__ float sD[64][66], sU[64][66], sB[64][20];
    const int t = threadIdx.x, wid = t >> 6, lane = t & 63;
    const int nl = lane & 3;
    const int dloc = wid * 16 + (lane >> 2);
    const int dblk = blockIdx.x, chunk = blockIdx.y, dirb = blockIdx.z;
    const int d = dblk * 64 + dloc, dir = dirb >> 1;
    const int T0 = chunk * SCL;
    f32x4 Av = *(const f32x4*)((dir ? Alb : Alf) + d * 16 + nl * 4);
    float An2[4] = {-expf(Av.x) * 1.44269504f, -expf(Av.y) * 1.44269504f,
                    -expf(Av.z) * 1.44269504f, -expf(Av.w) * 1.44269504f};
    const float* dp = delta + ((long)dirb * 2048 + dblk * 64) * 1024;
    const float* up = u     + ((long)dirb * 2048 + dblk * 64) * 1024;
    const float* Bp = xdbl  + ((long)dirb * 96 + 64) * 1024;

    // stage whole chunk: sD/sU 64d x 64t, sB 64t x 16n
#pragma unroll
    for (int rep = 0; rep < 4; ++rep) {
        int ii = rep * 256 + t;
        int dd = ii >> 4, q = ii & 15;
        *(f32x4*)&sD[dd][q * 4] = *(const f32x4*)&dp[(long)dd * 1024 + T0 + q * 4];
        *(f32x4*)&sU[dd][q * 4] = *(const f32x4*)&up[(long)dd * 1024 + T0 + q * 4];
    }
#pragma unroll
    for (int rep = 0; rep < 4; ++rep) {
        int ii = rep * 256 + t;
        int n = ii >> 6, tt = ii & 63;
        sB[tt][n] = Bp[(long)n * 1024 + T0 + tt];
    }
    __syncthreads();

    float h[4] = {0.f, 0.f, 0.f, 0.f};
    float S = 0.f;
#pragma unroll 4
    for (int g = 0; g < 16; ++g) {
        f32x4 dlv = *(const f32x4*)&sD[dloc][g * 4];
        f32x4 uuv = *(const f32x4*)&sU[dloc][g * 4];
        float dls[4] = {dlv.x, dlv.y, dlv.z, dlv.w};
        float uus[4] = {uuv.x, uuv.y, uuv.z, uuv.w};
#pragma unroll
        for (int r4 = 0; r4 < 4; ++r4) {
            f32x4 Bv = *(const f32x4*)&sB[g * 4 + r4][nl * 4];
            float Bs[4] = {Bv.x, Bv.y, Bv.z, Bv.w};
            float dl = dls[r4], t1 = dl * uus[r4];
            S += dl;
#pragma unroll
            for (int r = 0; r < 4; ++r)
                h[r] = fmaf(__builtin_amdgcn_exp2f(dl * An2[r]), h[r], t1 * Bs[r]);
        }
    }
    long cb = (((long)dirb * SCH + chunk) * 2048 + d) * 16 + nl * 4;
    *(f32x4*)&hend[cb]  = (f32x4){h[0], h[1], h[2], h[3]};
    *(f32x4*)&aprod[cb] = (f32x4){__builtin_amdgcn_exp2f(S * An2[0]),
                                  __builtin_amdgcn_exp2f(S * An2[1]),
                                  __builtin_amdgcn_exp2f(S * An2[2]),
                                  __builtin_amdgcn_exp2f(S * An2[3])};
}

// scan v4 pass 2: sequential carry combine across SCH chunks.
__global__ __launch_bounds__(256)
void scan_carry_kernel(const float* __restrict__ hend, const float* __restrict__ aprod,
                       float* __restrict__ hinit)
{
    int f = blockIdx.x * 256 + threadIdx.x;   // (dirb, d*16+n)
    int dn = f & 32767;
    int dirb = f >> 15;
    long base = (long)dirb * SCH * 32768 + dn;
    float hcur = 0.f;
#pragma unroll
    for (int c = 0; c < SCH; ++c) {
        hinit[base + (long)c * 32768] = hcur;
        hcur = hend[base + (long)c * 32768]
             + aprod[base + (long)c * 32768] * hcur;
    }
}

// scan v4 pass 3: rescan chunk from hinit, emit y. Whole-chunk staging.
__global__ __launch_bounds__(256)
void scan_p3_kernel(const float* __restrict__ u, const float* __restrict__ delta,
                    const float* __restrict__ xdbl,
                    const float* __restrict__ Alf, const float* __restrict__ Alb,
                    const float* __restrict__ Df, const float* __restrict__ Db,
                    const float* __restrict__ hinit, float* __restrict__ y)
{
    __shared__ float sD[64][66], sU[64][66], sB[64][20], sC[64][20];
    const int t = threadIdx.x, wid = t >> 6, lane = t & 63;
    const int nl = lane & 3;
    const int dloc = wid * 16 + (lane >> 2);
    const int dblk = blockIdx.x, chunk = blockIdx.y, dirb = blockIdx.z;
    const int d = dblk * 64 + dloc, dir = dirb >> 1;
    const int T0 = chunk * SCL;
    f32x4 Av = *(const f32x4*)((dir ? Alb : Alf) + d * 16 + nl * 4);
    float An2[4] = {-expf(Av.x) * 1.44269504f, -expf(Av.y) * 1.44269504f,
                    -expf(Av.z) * 1.44269504f, -expf(Av.w) * 1.44269504f};
    const float Dd = (dir ? Db : Df)[d];
    const float* dp = delta + ((long)dirb * 2048 + dblk * 64) * 1024;
    const float* up = u     + ((long)dirb * 2048 + dblk * 64) * 1024;
    const float* Bp = xdbl  + ((long)dirb * 96 + 64) * 1024;
    const float* Cp = xdbl  + ((long)dirb * 96 + 80) * 1024;
    float* yrow = y + ((long)dirb * 2048 + d) * 1024;

#pragma unroll
    for (int rep = 0; rep < 4; ++rep) {
        int ii = rep * 256 + t;
        int dd = ii >> 4, q = ii & 15;
        *(f32x4*)&sD[dd][q * 4] = *(const f32x4*)&dp[(long)dd * 1024 + T0 + q * 4];
        *(f32x4*)&sU[dd][q * 4] = *(const f32x4*)&up[(long)dd * 1024 + T0 + q * 4];
    }
#pragma unroll
    for (int rep = 0; rep < 4; ++rep) {
        int ii = rep * 256 + t;
        int n = ii >> 6, tt = ii & 63;
        sB[tt][n] = Bp[(long)n * 1024 + T0 + tt];
        sC[tt][n] = Cp[(long)n * 1024 + T0 + tt];
    }
    long cb = (((long)dirb * SCH + chunk) * 2048 + d) * 16 + nl * 4;
    f32x4 h0v = *(const f32x4*)&hinit[cb];
    float h[4] = {h0v.x, h0v.y, h0v.z, h0v.w};
    const bool m[4] = {nl == 0, nl == 1, nl == 2, nl == 3};
    __syncthreads();

#pragma unroll 4
    for (int g = 0; g < 16; ++g) {
        f32x4 dlv = *(const f32x4*)&sD[dloc][g * 4];
        f32x4 uuv = *(const f32x4*)&sU[dloc][g * 4];
        float dls[4] = {dlv.x, dlv.y, dlv.z, dlv.w};
        float uus[4] = {uuv.x, uuv.y, uuv.z, uuv.w};
        float keep = 0.f;
#pragma unroll
        for (int r4 = 0; r4 < 4; ++r4) {
            f32x4 Bv = *(const f32x4*)&sB[g * 4 + r4][nl * 4];
            f32x4 Cv = *(const f32x4*)&sC[g * 4 + r4][nl * 4];
            float Bs[4] = {Bv.x, Bv.y, Bv.z, Bv.w};
            float Cs[4] = {Cv.x, Cv.y, Cv.z, Cv.w};
            float dl = dls[r4], uu = uus[r4];
            float t1 = dl * uu;
#pragma unroll
            for (int r = 0; r < 4; ++r)
                h[r] = fmaf(__builtin_amdgcn_exp2f(dl * An2[r]), h[r], t1 * Bs[r]);
            float p = h[0] * Cs[0];
            p = fmaf(h[1], Cs[1], p);
            p = fmaf(h[2], Cs[2], p);
            p = fmaf(h[3], Cs[3], p);
            p = dpp_add<0xB1>(p);      // quad xor1
            p = dpp_add<0x4E>(p);      // quad xor2 -> full 16-n sum in all 4 lanes
            float fy = fmaf(Dd, uu, p);
            keep = m[r4] ? fy : keep;
        }
        yrow[T0 + g * 4 + nl] = keep;
    }
}

// G = silu(z) * (y_f + rev y_b), written TRANSPOSED as fp16 GT[b][l][d].
__global__ __launch_bounds__(256)
void combine_T_kernel(const float* __restrict__ xz, const float* __restrict__ y,
                      _Float16* __restrict__ GT)
{
    __shared__ float Ls[64][65];
    const int d0 = blockIdx.x * 64, l0 = blockIdx.y * 64, b = blockIdx.z;
    const int t = threadIdx.x;
#pragma unroll
    for (int rep = 0; rep < 4; ++rep) {
        int i = rep * 256 + t;
        int dl = i >> 4;
        int lq = (i & 15) * 4;
        const float* zp  = xz + ((long)b * 4096 + 2048 + d0 + dl) * 1024 + l0 + lq;
        const float* yfp = y  + ((long)(b)     * 2048 + d0 + dl) * 1024 + l0 + lq;
        const float* ybp = y  + ((long)(2 + b) * 2048 + d0 + dl) * 1024 + (1020 - l0 - lq);
        float4 vz = *(const float4*)zp;
        float4 vf = *(const float4*)yfp;
        float4 vb = *(const float4*)ybp;
        float zz[4]  = {vz.x, vz.y, vz.z, vz.w};
        float ff[4]  = {vf.x, vf.y, vf.z, vf.w};
        float bbv[4] = {vb.w, vb.z, vb.y, vb.x};
#pragma unroll
        for (int qq = 0; qq < 4; ++qq) {
            float z = zz[qq];
            float sz = z / (1.f + __builtin_amdgcn_exp2f(-z * 1.44269504f));
            Ls[dl][lq + qq] = sz * (ff[qq] + bbv[qq]);
        }
    }
    __syncthreads();
#pragma unroll
    for (int rep = 0; rep < 4; ++rep) {
        int i = rep * 256 + t;
        int ll = i >> 4;
        int dq = (i & 15) * 4;
        f16x4 h = {(_Float16)Ls[dq][ll], (_Float16)Ls[dq + 1][ll],
                   (_Float16)Ls[dq + 2][ll], (_Float16)Ls[dq + 3][ll]};
        *(f16x4*)(GT + ((long)(b * 1024 + l0 + ll)) * 2048 + d0 + dq) = h;
    }
}

extern "C" void kernel_launch(void* const* d_in, const int* in_sizes, int n_in,
                              void* d_out, int out_size, void* d_ws, size_t ws_size,
                              hipStream_t stream)
{
    const float* hidden   = (const float*)d_in[0];
    const float* inproj_w = (const float*)d_in[1];
    const float* conv_w   = (const float*)d_in[2];
    const float* conv_b   = (const float*)d_in[3];
    const float* xproj_w  = (const float*)d_in[4];
    const float* dtproj_w = (const float*)d_in[5];
    const float* dt_bias  = (const float*)d_in[6];
    const float* A_log    = (const float*)d_in[7];
    const float* D_skip   = (const float*)d_in[8];
    const float* convb_w  = (const float*)d_in[9];
    const float* convb_b  = (const float*)d_in[10];
    const float* xprojb_w = (const float*)d_in[11];
    const float* dtprojb_w= (const float*)d_in[12];
    const float* dtb_bias = (const float*)d_in[13];
    const float* Ab_log   = (const float*)d_in[14];
    const float* Db_skip  = (const float*)d_in[15];
    const float* outproj_w= (const float*)d_in[16];
    float* out = (float*)d_out;

    float* ws    = (float*)d_ws;
    float* xz    = ws;
    float* u     = ws + 8388608;
    float* xdbl  = ws + 16777216;
    float* delta = ws + 17170432;
    float* y     = ws + 25559040;
    // fp16 / scratch aliases in temporally-dead regions:
    _Float16* H16    = (_Float16*)u;
    _Float16* Win16  = (_Float16*)(u + 1048576);
    float*    xpb    = delta;                       // x_proj partials
    _Float16* GT     = (_Float16*)delta;            // after scan
    _Float16* Wout16 = (_Float16*)y;                // after combine
    _Float16* dw16   = (_Float16*)y;                // pre-scan scratch
    float*    bcat   = y + 131072;
    _Float16* xw16   = (_Float16*)(y + 135168);
    // scan carry buffers (SCH=16 -> 2M f32 each):
    float* hend  = y;               // y dead until p3 writes it
    float* aprod = y + 2097152;
    float* hinit = xz;              // b0 x-half dead after conv

    // 0) f32 -> fp16 conversions
    hipLaunchKernelGGL(cvt_f16_kernel, dim3(2048), dim3(256), 0, stream,
        hidden, H16, 2097152);
    hipLaunchKernelGGL(cvt_f16_kernel, dim3(4096), dim3(256), 0, stream,
        inproj_w, Win16, 4194304);

    // 0b) weight concat/convert
    hipLaunchKernelGGL(concat_weights, dim3(768), dim3(256), 0, stream,
        xproj_w, xprojb_w, dtproj_w, dtprojb_w, dt_bias, dtb_bias,
        xw16, dw16, bcat);

    // 1) in_proj MFMA
    hipLaunchKernelGGL((gemm_nt_f16<2, 2, 4, 4>),
        dim3(32, 8, 2), dim3(256), 0, stream,
        H16, Win16, xz, 1024, 1024, 1048576L, 4194304L);

    // 2) conv + silu
    hipLaunchKernelGGL(conv_silu_kernel, dim3(32768), dim3(256), 0, stream,
        xz, conv_w, conv_b, convb_w, convb_b, u);

    // 3) x_proj MFMA split-K + reduce
    hipLaunchKernelGGL(xproj_f16_kernel, dim3(8, XP_SK, 4), dim3(256), 0, stream,
        u, xw16, xpb);
    hipLaunchKernelGGL(xreduce_kernel, dim3(384), dim3(256), 0, stream,
        xpb, xdbl);

    // 4) dt_proj fp16 MFMA + softplus
    hipLaunchKernelGGL(dtproj_f16_kernel, dim3(16, 8, 4), dim3(256), 0, stream,
        xdbl, dw16, bcat, delta);

    // 5) scan v4: p1 (local) -> carry -> p3 (emit y)
    hipLaunchKernelGGL(scan_p1_kernel, dim3(32, SCH, 4), dim3(256), 0, stream,
        u, delta, xdbl, A_log, Ab_log, hend, aprod);
    hipLaunchKernelGGL(scan_carry_kernel, dim3(512), dim3(256), 0, stream,
        hend, aprod, hinit);
    hipLaunchKernelGGL(scan_p3_kernel, dim3(32, SCH, 4), dim3(256), 0, stream,
        u, delta, xdbl, A_log, Ab_log, D_skip, Db_skip, hinit, y);

    // 6) combine -> GT fp16
    hipLaunchKernelGGL(combine_T_kernel, dim3(32, 16, 2), dim3(256), 0, stream,
        xz, y, GT);

    // 7) W_out -> fp16
    hipLaunchKernelGGL(cvt_f16_kernel, dim3(2048), dim3(256), 0, stream,
        outproj_w, Wout16, 2097152);

    // 8) out_proj MFMA
    hipLaunchKernelGGL((gemm_nt_f16<4, 1, 2, 4>),
        dim3(32, 8, 1), dim3(256), 0, stream,
        Wout16, GT, out, 2048, 1024, 0L, 0L);
}